// Round 3
// baseline (316.440 us; speedup 1.0000x reference)
//
#include <hip/hip_runtime.h>
#include <math.h>

// NoisyTopkRouter: B=8,S=4096,D=1024,E=64,k=2
// R3: fp32-accurate GEMM via fp16x3 MFMA emulation (no fp32 MFMA on CDNA4).
//   x = x_hi(fp16) + x_lo/2048 (fp16, scaled to avoid fp16 denorm flush)
//   C = A_hi*B_hi  +  (A_hi*B_lo' + A_lo'*B_hi) / 2048      (lo*lo ~2^-22, dropped)
// Tile: 64 tok x 128 out per block, 128 thr = 2 waves, each wave 32 tok.
// mfma_f32_16x16x32_f16: A[m=lane&15][k=(lane>>4)*8+j], B[n=lane&15][k=...],
// C/D col=lane&15,row=(lane>>4)*4+reg (HW-verified layouts).
// Verified R2 epilogue (softplus/softmax/top2) kept unchanged.

#define DIM 1024
#define NEXP 64
#define TOK 64
#define LS 40          // staging row stride in halves (80B: 16B-aligned, bank-balanced)
#define CS 132         // epilogue Cs row stride in floats
#define LOSCALE 2048.0f
#define INV_LOSCALE (1.0f / 2048.0f)

using half4v = __attribute__((ext_vector_type(4))) _Float16;
using half8v = __attribute__((ext_vector_type(8))) _Float16;
using floatx4 = __attribute__((ext_vector_type(4))) float;

__device__ inline void split4(const float4 v, half4v& hi, half4v& lo) {
    _Float16 h0 = (_Float16)v.x, h1 = (_Float16)v.y,
             h2 = (_Float16)v.z, h3 = (_Float16)v.w;
    hi = (half4v){h0, h1, h2, h3};
    lo = (half4v){(_Float16)((v.x - (float)h0) * LOSCALE),
                  (_Float16)((v.y - (float)h1) * LOSCALE),
                  (_Float16)((v.z - (float)h2) * LOSCALE),
                  (_Float16)((v.w - (float)h3) * LOSCALE)};
}

#define MFMA(a, b, c) __builtin_amdgcn_mfma_f32_16x16x32_f16((a), (b), (c), 0, 0, 0)

__global__ __launch_bounds__(128, 2)
void noisy_topk_router_kernel(const float* __restrict__ h,
                              const float* __restrict__ Wl,
                              const float* __restrict__ bl,
                              const float* __restrict__ Wn,
                              const float* __restrict__ bn,
                              const float* __restrict__ noise,
                              float* __restrict__ out,
                              int M)
{
    // union: staging (30720B) then epilogue Cs[64][132] (33792B)
    __shared__ float smem[TOK * CS];
    _Float16* As_hi = (_Float16*)smem;          // [64][LS]
    _Float16* As_lo = As_hi + TOK * LS;
    _Float16* Bs_hi = As_lo + TOK * LS;         // [128][LS]
    _Float16* Bs_lo = Bs_hi + 128 * LS;

    const int tid  = threadIdx.x;               // 0..127
    const int wave = tid >> 6;                  // 0..1
    const int lane = tid & 63;
    const int tok0 = blockIdx.x * TOK;

    // global staging map: 8 lanes per row, 8 float4 along k
    const int grow = tid >> 3;                  // 0..15 (+16r)
    const int gkq  = tid & 7;                   // float4 slot in 32-k tile

    const float* Wp[8];
#pragma unroll
    for (int r = 0; r < 8; r++) {
        int e = grow + 16 * r;
        Wp[r] = ((e < NEXP) ? (Wl + (size_t)e * DIM)
                            : (Wn + (size_t)(e - NEXP) * DIM)) + gkq * 4;
    }
    const float* hp = h + (size_t)(tok0 + grow) * DIM + gkq * 4;

    // MFMA fragment LDS offsets
    const int frow = lane & 15;
    const int fk   = (lane >> 4) * 8;
    const int aoff0 = (wave * 32 + frow) * LS + fk;   // m-chunk 0
    const int aoff1 = aoff0 + 16 * LS;                // m-chunk 1
    const int boff  = frow * LS + fk;                 // + nc*16*LS

    floatx4 acc1[2][8], acc2[2][8];
#pragma unroll
    for (int mc = 0; mc < 2; mc++)
#pragma unroll
        for (int nc = 0; nc < 8; nc++) {
            acc1[mc][nc] = (floatx4){0.f, 0.f, 0.f, 0.f};
            acc2[mc][nc] = (floatx4){0.f, 0.f, 0.f, 0.f};
        }

    // prefetch first A tile (h stream is the HBM-bound part)
    float4 av[4];
#pragma unroll
    for (int r = 0; r < 4; r++)
        av[r] = *(const float4*)(hp + (size_t)(16 * r) * DIM);

    for (int kc = 0; kc < DIM; kc += 32) {
        __syncthreads();    // previous tile's MFMA reads done
        // ---- stage A (from prefetch regs) ----
#pragma unroll
        for (int r = 0; r < 4; r++) {
            half4v hi, lo;
            split4(av[r], hi, lo);
            *(half4v*)(As_hi + (grow + 16 * r) * LS + gkq * 4) = hi;
            *(half4v*)(As_lo + (grow + 16 * r) * LS + gkq * 4) = lo;
        }
        // ---- stage B (W is L2-hot: load-use in phase) ----
#pragma unroll
        for (int r = 0; r < 8; r++) {
            float4 wv = *(const float4*)(Wp[r] + kc);
            half4v hi, lo;
            split4(wv, hi, lo);
            *(half4v*)(Bs_hi + (grow + 16 * r) * LS + gkq * 4) = hi;
            *(half4v*)(Bs_lo + (grow + 16 * r) * LS + gkq * 4) = lo;
        }
        __syncthreads();
        // ---- prefetch next A tile ----
        if (kc + 32 < DIM) {
#pragma unroll
            for (int r = 0; r < 4; r++)
                av[r] = *(const float4*)(hp + (size_t)(16 * r) * DIM + kc + 32);
        }
        // ---- MFMA: one 16x16x32 covers the whole 32-k tile ----
        half8v aH0 = *(const half8v*)(As_hi + aoff0);
        half8v aL0 = *(const half8v*)(As_lo + aoff0);
        half8v aH1 = *(const half8v*)(As_hi + aoff1);
        half8v aL1 = *(const half8v*)(As_lo + aoff1);
#pragma unroll
        for (int nc = 0; nc < 8; nc++) {
            half8v bH = *(const half8v*)(Bs_hi + nc * 16 * LS + boff);
            half8v bL = *(const half8v*)(Bs_lo + nc * 16 * LS + boff);
            acc1[0][nc] = MFMA(aH0, bH, acc1[0][nc]);
            acc1[1][nc] = MFMA(aH1, bH, acc1[1][nc]);
            acc2[0][nc] = MFMA(aH0, bL, acc2[0][nc]);
            acc2[1][nc] = MFMA(aH1, bL, acc2[1][nc]);
            acc2[0][nc] = MFMA(aL0, bH, acc2[0][nc]);
            acc2[1][nc] = MFMA(aL1, bH, acc2[1][nc]);
        }
    }
    __syncthreads();   // staging reads done; overwrite with Cs

    // ---- combine terms, write Cs[token][expert] ----
    float* Cs = smem;
    {
        const int trow0 = wave * 32 + (lane >> 4) * 4;
        const int col   = lane & 15;
#pragma unroll
        for (int mc = 0; mc < 2; mc++)
#pragma unroll
            for (int nc = 0; nc < 8; nc++) {
                floatx4 c = acc1[mc][nc] + acc2[mc][nc] * INV_LOSCALE;
#pragma unroll
                for (int j = 0; j < 4; j++)
                    Cs[(trow0 + mc * 16 + j) * CS + nc * 16 + col] = c[j];
            }
    }
    __syncthreads();

    // ---- epilogue: one wave per token, lane = expert (verified in R1/R2) ----
    const float blv = bl[lane];
    const float bnv = bn[lane];
    const size_t offIx   = (size_t)M * NEXP;
    const size_t offFull = offIx + (size_t)M * 2;

    for (int t = wave; t < TOK; t += 2) {
        const int gt = tok0 + t;
        float logit = Cs[t * CS + lane] + blv;
        float sraw  = Cs[t * CS + 64 + lane] + bnv;
        // softplus (matches jax.nn.softplus)
        float stdv = fmaxf(sraw, 0.f) + log1pf(expf(-fabsf(sraw)));
        float nz = noise[(size_t)gt * NEXP + lane];
        float noisy = fmaf(nz, stdv, logit);

        // full softmax over 64 lanes
        float m = noisy;
#pragma unroll
        for (int o = 32; o > 0; o >>= 1) m = fmaxf(m, __shfl_xor(m, o, 64));
        float p = expf(noisy - m);
        float s = p;
#pragma unroll
        for (int o = 32; o > 0; o >>= 1) s += __shfl_xor(s, o, 64);
        float fullp = p / s;

        // argmax #1 (ties -> lowest index, matching lax.top_k)
        float v = noisy; int idx = lane;
#pragma unroll
        for (int o = 32; o > 0; o >>= 1) {
            float ov = __shfl_xor(v, o, 64);
            int   oi = __shfl_xor(idx, o, 64);
            if (ov > v || (ov == v && oi < idx)) { v = ov; idx = oi; }
        }
        const float v1 = v; const int i1 = idx;
        // argmax #2
        v = (lane == i1) ? -INFINITY : noisy; idx = lane;
#pragma unroll
        for (int o = 32; o > 0; o >>= 1) {
            float ov = __shfl_xor(v, o, 64);
            int   oi = __shfl_xor(idx, o, 64);
            if (ov > v || (ov == v && oi < idx)) { v = ov; idx = oi; }
        }
        const float v2 = v; const int i2 = idx;

        // sparse softmax over {i1,i2}: max = v1
        float e2 = expf(v2 - v1);
        float den = 1.f + e2;
        float routep = (lane == i1) ? (1.f / den) : ((lane == i2) ? (e2 / den) : 0.f);

        out[(size_t)gt * NEXP + lane] = routep;
        out[offFull + (size_t)gt * NEXP + lane] = fullp;
        if (lane == 0) {
            out[offIx + (size_t)gt * 2 + 0] = (float)i1;
            out[offIx + (size_t)gt * 2 + 1] = (float)i2;
        }
    }
}

extern "C" void kernel_launch(void* const* d_in, const int* in_sizes, int n_in,
                              void* d_out, int out_size, void* d_ws, size_t ws_size,
                              hipStream_t stream) {
    const float* h     = (const float*)d_in[0];
    const float* Wl    = (const float*)d_in[1];
    const float* bl    = (const float*)d_in[2];
    const float* Wn    = (const float*)d_in[3];
    const float* bn    = (const float*)d_in[4];
    const float* noise = (const float*)d_in[5];
    float* out = (float*)d_out;

    const int M = in_sizes[0] / DIM;          // B*S = 32768
    const int grid = M / TOK;                 // 512 blocks

    noisy_topk_router_kernel<<<grid, 128, 0, stream>>>(h, Wl, bl, Wn, bn, noise, out, M);
}

// Round 4
// 250.545 us; speedup vs baseline: 1.2630x; 1.2630x over previous
//
#include <hip/hip_runtime.h>
#include <math.h>

// NoisyTopkRouter: B=8,S=4096,D=1024,E=64,k=2
// R4: split-K fp16x3-emulated MFMA GEMM (32x32x16) + separate epilogue kernel.
//   C = A_hi*B_hi + (A_hi*B_lo' + A_lo'*B_hi)/2048   (fp32-accurate, R3-verified)
// GEMM: 256 thr = 4 waves, each wave 32 tokens x 128 outs, A direct
// global->fragment (no LDS), B double-buffered in LDS, 1 barrier/k-tile.
// Split-K=2 doubles occupancy (2048 waves = 2/SIMD): split0 partial -> out's
// route+full regions (exactly M*128 floats), split1 -> ws. Epilogue kernel
// sums partials + bias, then the R1/R2/R3-verified softplus/softmax/top2.

#define DIM 1024
#define NEXP 64
#define LSB 40            // B staging row stride in halves (80B = 5*16B, 2-way banks)
#define LOSCALE 2048.0f
#define INV_LOSCALE (1.0f / 2048.0f)

using half4v  = __attribute__((ext_vector_type(4)))  _Float16;
using half8v  = __attribute__((ext_vector_type(8)))  _Float16;
using floatx16 = __attribute__((ext_vector_type(16))) float;

__device__ inline void split4(const float4 v, half4v& hi, half4v& lo) {
    _Float16 h0 = (_Float16)v.x, h1 = (_Float16)v.y,
             h2 = (_Float16)v.z, h3 = (_Float16)v.w;
    hi = (half4v){h0, h1, h2, h3};
    lo = (half4v){(_Float16)((v.x - (float)h0) * LOSCALE),
                  (_Float16)((v.y - (float)h1) * LOSCALE),
                  (_Float16)((v.z - (float)h2) * LOSCALE),
                  (_Float16)((v.w - (float)h3) * LOSCALE)};
}

__device__ inline half8v mk8(const half4v a, const half4v b) {
    return (half8v){a[0], a[1], a[2], a[3], b[0], b[1], b[2], b[3]};
}

#define MFMA32(a, b, c) __builtin_amdgcn_mfma_f32_32x32x16_f16((a), (b), (c), 0, 0, 0)

// ---------------- GEMM kernel ----------------
__global__ __launch_bounds__(256, 2)
void router_gemm(const float* __restrict__ h, const float* __restrict__ Wl,
                 const float* __restrict__ Wn, float* __restrict__ outR,
                 float* __restrict__ outF, float* __restrict__ ws,
                 int M, int kLen)
{
    // LDS: 2 buffers x [hi 128xLSB | lo 128xLSB] halves = 40960 B
    __shared__ _Float16 lds[2 * 2 * 128 * LSB];

    const int tid  = threadIdx.x;
    const int wv   = tid >> 6;          // wave 0..3 -> tokens [32wv, 32wv+32)
    const int lane = tid & 63;
    const int row31 = lane & 31;        // token-in-tile / expert-in-nc
    const int oct   = lane >> 5;        // k-octet selector
    const int tok0  = blockIdx.x * 128;
    const int kStart = blockIdx.y * kLen;
    const int nTiles = kLen >> 5;       // 32-k tiles

    float* d0 = (blockIdx.y == 0) ? outR : ws;                      // experts 0..63
    float* d1 = (blockIdx.y == 0) ? outF : ws + (size_t)M * NEXP;   // experts 64..127

    // B staging: thread covers rows brow+32r (r=0..3), float4 slot bkq
    const int brow = tid >> 3;          // 0..31
    const int bkq  = tid & 7;
    const float* wp[4];
#pragma unroll
    for (int r = 0; r < 4; r++) {
        int e = brow + 32 * r;
        wp[r] = ((e < NEXP) ? (Wl + (size_t)e * DIM)
                            : (Wn + (size_t)(e - NEXP) * DIM)) + kStart + bkq * 4;
    }
    // A: lane reads its own fragment rows directly from global
    const float* hp = h + (size_t)(tok0 + wv * 32 + row31) * DIM + kStart + oct * 8;

    floatx16 acc1[4], acc2[4];
#pragma unroll
    for (int nc = 0; nc < 4; nc++)
#pragma unroll
        for (int i = 0; i < 16; i++) { acc1[nc][i] = 0.f; acc2[nc][i] = 0.f; }

    float4 breg[4], areg[4];
    // ---- prologue: B(t0)->buf0, load B(t1), A(t0) ----
#pragma unroll
    for (int r = 0; r < 4; r++) breg[r] = *(const float4*)(wp[r]);
    areg[0] = *(const float4*)(hp);
    areg[1] = *(const float4*)(hp + 4);
    areg[2] = *(const float4*)(hp + 16);
    areg[3] = *(const float4*)(hp + 20);
    {
        _Float16* Bhi = lds;
        _Float16* Blo = lds + 128 * LSB;
#pragma unroll
        for (int r = 0; r < 4; r++) {
            half4v hi, lo; split4(breg[r], hi, lo);
            int rr = brow + 32 * r;
            *(half4v*)(Bhi + rr * LSB + bkq * 4) = hi;
            *(half4v*)(Blo + rr * LSB + bkq * 4) = lo;
        }
    }
    if (nTiles > 1)
#pragma unroll
        for (int r = 0; r < 4; r++) breg[r] = *(const float4*)(wp[r] + 32);
    __syncthreads();

    for (int kt = 0; kt < nTiles; kt++) {
        const int p = kt & 1;
        // 1. store B(kt+1) regs -> buf[p^1]
        if (kt + 1 < nTiles) {
            _Float16* Bhi = lds + (p ^ 1) * (2 * 128 * LSB);
            _Float16* Blo = Bhi + 128 * LSB;
#pragma unroll
            for (int r = 0; r < 4; r++) {
                half4v hi, lo; split4(breg[r], hi, lo);
                int rr = brow + 32 * r;
                *(half4v*)(Bhi + rr * LSB + bkq * 4) = hi;
                *(half4v*)(Blo + rr * LSB + bkq * 4) = lo;
            }
        }
        // 2. issue B loads (kt+2)
        if (kt + 2 < nTiles)
#pragma unroll
            for (int r = 0; r < 4; r++)
                breg[r] = *(const float4*)(wp[r] + 32 * (kt + 2));
        // 3. split A(kt) into fragments
        half8v aH[2], aL[2];
#pragma unroll
        for (int ks = 0; ks < 2; ks++) {
            half4v h0, l0, h1, l1;
            split4(areg[2 * ks], h0, l0);
            split4(areg[2 * ks + 1], h1, l1);
            aH[ks] = mk8(h0, h1);
            aL[ks] = mk8(l0, l1);
        }
        // 4. issue A loads (kt+1)
        if (kt + 1 < nTiles) {
            const float* hq = hp + 32 * (kt + 1);
            areg[0] = *(const float4*)(hq);
            areg[1] = *(const float4*)(hq + 4);
            areg[2] = *(const float4*)(hq + 16);
            areg[3] = *(const float4*)(hq + 20);
        }
        // 5. MFMA from buf[p]
        {
            const _Float16* Bhi = lds + p * (2 * 128 * LSB);
            const _Float16* Blo = Bhi + 128 * LSB;
#pragma unroll
            for (int ks = 0; ks < 2; ks++) {
#pragma unroll
                for (int nc = 0; nc < 4; nc++) {
                    const int off = (nc * 32 + row31) * LSB + ks * 16 + oct * 8;
                    half8v bH = *(const half8v*)(Bhi + off);
                    half8v bL = *(const half8v*)(Blo + off);
                    acc1[nc] = MFMA32(aH[ks], bH, acc1[nc]);
                    acc2[nc] = MFMA32(aH[ks], bL, acc2[nc]);
                    acc2[nc] = MFMA32(aL[ks], bH, acc2[nc]);
                }
            }
        }
        __syncthreads();
    }

    // ---- write partial C: col=lane&31, row=(reg&3)+8*(reg>>2)+4*oct ----
#pragma unroll
    for (int nc = 0; nc < 4; nc++) {
        float* dst = (nc < 2) ? d0 : d1;
        const int ebase = (nc & 1) * 32 + row31;
#pragma unroll
        for (int i = 0; i < 16; i++) {
            int rowt = (i & 3) + 8 * (i >> 2) + 4 * oct;
            float c = acc1[nc][i] + acc2[nc][i] * INV_LOSCALE;
            dst[(size_t)(tok0 + wv * 32 + rowt) * NEXP + ebase] = c;
        }
    }
}

// ---------------- epilogue kernel ----------------
__global__ __launch_bounds__(256, 4)
void router_epilogue(const float* __restrict__ noise, const float* __restrict__ bl,
                     const float* __restrict__ bn, float* __restrict__ outR,
                     float* __restrict__ outIx, float* __restrict__ outF,
                     const float* __restrict__ ws, int M, int parts)
{
    const int tid = threadIdx.x;
    const int wv = tid >> 6, lane = tid & 63;
    const int t0 = blockIdx.x * 64 + wv * 16;
    const float blv = bl[lane], bnv = bn[lane];
    const float* wsF = ws + (size_t)M * NEXP;

    float c0r, c0f, c1r = 0.f, c1f = 0.f, nz;
    {
        size_t o = (size_t)t0 * NEXP + lane;
        c0r = outR[o]; c0f = outF[o]; nz = noise[o];
        if (parts == 2) { c1r = ws[o]; c1f = wsF[o]; }
    }

    for (int i = 0; i < 16; i++) {
        const int gt = t0 + i;
        const float xr = c0r + c1r + blv;
        const float xf = c0f + c1f + bnv;
        const float nzc = nz;
        if (i + 1 < 16) {   // prefetch next token (distinct addresses, no alias)
            size_t o = (size_t)(gt + 1) * NEXP + lane;
            c0r = outR[o]; c0f = outF[o]; nz = noise[o];
            if (parts == 2) { c1r = ws[o]; c1f = wsF[o]; }
        }
        // softplus (matches jax.nn.softplus)
        float stdv = fmaxf(xf, 0.f) + log1pf(expf(-fabsf(xf)));
        float noisy = fmaf(nzc, stdv, xr);

        // full softmax over 64 lanes
        float m = noisy;
#pragma unroll
        for (int o = 32; o > 0; o >>= 1) m = fmaxf(m, __shfl_xor(m, o, 64));
        float p = expf(noisy - m);
        float s = p;
#pragma unroll
        for (int o = 32; o > 0; o >>= 1) s += __shfl_xor(s, o, 64);
        float fullp = p / s;

        // argmax #1 (ties -> lowest index, matching lax.top_k)
        float v = noisy; int idx = lane;
#pragma unroll
        for (int o = 32; o > 0; o >>= 1) {
            float ov = __shfl_xor(v, o, 64);
            int   oi = __shfl_xor(idx, o, 64);
            if (ov > v || (ov == v && oi < idx)) { v = ov; idx = oi; }
        }
        const float v1 = v; const int i1 = idx;
        // argmax #2
        v = (lane == i1) ? -INFINITY : noisy; idx = lane;
#pragma unroll
        for (int o = 32; o > 0; o >>= 1) {
            float ov = __shfl_xor(v, o, 64);
            int   oi = __shfl_xor(idx, o, 64);
            if (ov > v || (ov == v && oi < idx)) { v = ov; idx = oi; }
        }
        const float v2 = v; const int i2 = idx;

        // sparse softmax over {i1,i2}
        float e2 = expf(v2 - v1);
        float den = 1.f + e2;
        float routep = (lane == i1) ? (1.f / den) : ((lane == i2) ? (e2 / den) : 0.f);

        outR[(size_t)gt * NEXP + lane] = routep;
        outF[(size_t)gt * NEXP + lane] = fullp;
        if (lane == 0) {
            outIx[(size_t)gt * 2 + 0] = (float)i1;
            outIx[(size_t)gt * 2 + 1] = (float)i2;
        }
    }
}

extern "C" void kernel_launch(void* const* d_in, const int* in_sizes, int n_in,
                              void* d_out, int out_size, void* d_ws, size_t ws_size,
                              hipStream_t stream) {
    const float* h     = (const float*)d_in[0];
    const float* Wl    = (const float*)d_in[1];
    const float* bl    = (const float*)d_in[2];
    const float* Wn    = (const float*)d_in[3];
    const float* bn    = (const float*)d_in[4];
    const float* noise = (const float*)d_in[5];
    float* out = (float*)d_out;

    const int M = in_sizes[0] / DIM;                 // 32768
    float* outR  = out;                              // [M,64]
    float* outIx = out + (size_t)M * NEXP;           // [M,2]
    float* outF  = outIx + (size_t)M * 2;            // [M,64]
    float* ws    = (float*)d_ws;

    const int splits = (ws_size >= (size_t)M * 128 * sizeof(float)) ? 2 : 1;
    const int kLen = DIM / splits;

    dim3 grid(M / 128, splits);
    router_gemm<<<grid, 256, 0, stream>>>(h, Wl, Wn, outR, outF, ws, M, kLen);
    router_epilogue<<<M / 64, 256, 0, stream>>>(noise, bl, bn, outR, outIx, outF,
                                                ws, M, splits);
}

// Round 5
// 239.418 us; speedup vs baseline: 1.3217x; 1.0465x over previous
//
#include <hip/hip_runtime.h>
#include <math.h>

// NoisyTopkRouter: B=8,S=4096,D=1024,E=64,k=2
// R5: single fused kernel. fp16x3-emulated MFMA GEMM (32x32x16):
//   C = A_hi*B_hi + (A_hi*B_lo' + A_lo'*B_hi)/2048   (fp32-accurate, verified R3/R4)
// Block = 64 tok x 128 outs, 512 thr = 8 waves (2 token-groups x 4 expert-groups,
// each wave one 32x32 tile over K=1024). A and B both staged hi/lo in LDS,
// double-buffered, one barrier per 32-k tile. Epilogue fused via Cs overlay
// (R1-R4 verified softplus/softmax/top2 math verbatim). No split-K partials.

#define DIM 1024
#define NEXP 64
#define LS 40               // staging row stride in halves (80B, 16B-aligned)
#define CS 132              // Cs row stride in floats
#define HALF_BUF 15360      // halves per dbuf buffer (A 2*2560 + B 2*5120)
#define A_LO 2560
#define B_HI 5120
#define B_LO 10240
#define LOSCALE 2048.0f
#define INV_LOSCALE (1.0f / 2048.0f)

using half4v   = __attribute__((ext_vector_type(4)))  _Float16;
using half8v   = __attribute__((ext_vector_type(8)))  _Float16;
using floatx16 = __attribute__((ext_vector_type(16))) float;

__device__ inline void split4(const float4 v, half4v& hi, half4v& lo) {
    _Float16 h0 = (_Float16)v.x, h1 = (_Float16)v.y,
             h2 = (_Float16)v.z, h3 = (_Float16)v.w;
    hi = (half4v){h0, h1, h2, h3};
    lo = (half4v){(_Float16)((v.x - (float)h0) * LOSCALE),
                  (_Float16)((v.y - (float)h1) * LOSCALE),
                  (_Float16)((v.z - (float)h2) * LOSCALE),
                  (_Float16)((v.w - (float)h3) * LOSCALE)};
}

#define MFMA32(a, b, c) __builtin_amdgcn_mfma_f32_32x32x16_f16((a), (b), (c), 0, 0, 0)

__global__ __launch_bounds__(512, 4)
void router_fused(const float* __restrict__ h,  const float* __restrict__ Wl,
                  const float* __restrict__ bl, const float* __restrict__ Wn,
                  const float* __restrict__ bn, const float* __restrict__ noise,
                  float* __restrict__ outR, float* __restrict__ outIx,
                  float* __restrict__ outF, int M)
{
    __shared__ _Float16 lds[2 * HALF_BUF];   // 61440 B; Cs overlay needs 33792 B

    const int tid   = threadIdx.x;           // 0..511
    const int wv    = tid >> 6;              // 0..7
    const int lane  = tid & 63;
    const int row31 = lane & 31;
    const int oct   = lane >> 5;
    const int tokg  = (wv >> 2) * 32;        // 0 or 32
    const int expg  = (wv & 3) * 32;         // 0,32,64,96
    const int tok0  = blockIdx.x * 64;

    // ---- staging maps (coalesced: 8 lanes cover 128B of one row) ----
    const int srow = tid >> 3;               // 0..63
    const int skq  = tid & 7;                // float4 slot in 32-k tile
    const float* hp  = h  + (size_t)(tok0 + srow) * DIM + skq * 4;
    const float* wp0 = Wl + (size_t)srow * DIM + skq * 4;   // experts 0..63
    const float* wp1 = Wn + (size_t)srow * DIM + skq * 4;   // experts 64..127
    const int sA  = srow * LS + skq * 4;          // A slot (halves)
    const int sB0 = B_HI + srow * LS + skq * 4;   // B row srow
    const int sB1 = B_HI + (srow + 64) * LS + skq * 4;

    // ---- fragment offsets ----
    const int aoffs = (tokg + row31) * LS + oct * 8;
    const int boffs = (expg + row31) * LS + oct * 8;

    floatx16 acc1, acc2;
#pragma unroll
    for (int i = 0; i < 16; i++) { acc1[i] = 0.f; acc2[i] = 0.f; }

    // ---- prologue: tile0 -> buf0, load tile1 ----
    float4 av  = *(const float4*)(hp);
    float4 bv0 = *(const float4*)(wp0);
    float4 bv1 = *(const float4*)(wp1);
    {
        half4v hi, lo;
        split4(av, hi, lo);
        *(half4v*)(lds + sA) = hi;        *(half4v*)(lds + A_LO + sA) = lo;
        split4(bv0, hi, lo);
        *(half4v*)(lds + sB0) = hi;       *(half4v*)(lds + B_LO - B_HI + sB0) = lo;
        split4(bv1, hi, lo);
        *(half4v*)(lds + sB1) = hi;       *(half4v*)(lds + B_LO - B_HI + sB1) = lo;
    }
    av  = *(const float4*)(hp + 32);
    bv0 = *(const float4*)(wp0 + 32);
    bv1 = *(const float4*)(wp1 + 32);
    __syncthreads();

    for (int t = 0; t < 32; t++) {
        // 1. store tile t+1 regs -> buf[(t+1)&1]
        if (t < 31) {
            _Float16* bufS = lds + ((t + 1) & 1) * HALF_BUF;
            half4v hi, lo;
            split4(av, hi, lo);
            *(half4v*)(bufS + sA) = hi;   *(half4v*)(bufS + A_LO + sA) = lo;
            split4(bv0, hi, lo);
            *(half4v*)(bufS + sB0) = hi;  *(half4v*)(bufS + B_LO - B_HI + sB0) = lo;
            split4(bv1, hi, lo);
            *(half4v*)(bufS + sB1) = hi;  *(half4v*)(bufS + B_LO - B_HI + sB1) = lo;
        }
        // 2. issue loads for tile t+2
        if (t < 30) {
            av  = *(const float4*)(hp  + 32 * (t + 2));
            bv0 = *(const float4*)(wp0 + 32 * (t + 2));
            bv1 = *(const float4*)(wp1 + 32 * (t + 2));
        }
        // 3. MFMA from buf[t&1]
        {
            const _Float16* bufC = lds + (t & 1) * HALF_BUF;
#pragma unroll
            for (int ks = 0; ks < 2; ks++) {
                half8v aH = *(const half8v*)(bufC + aoffs + ks * 16);
                half8v aL = *(const half8v*)(bufC + A_LO + aoffs + ks * 16);
                half8v bH = *(const half8v*)(bufC + B_HI + boffs + ks * 16);
                half8v bL = *(const half8v*)(bufC + B_LO + boffs + ks * 16);
                acc1 = MFMA32(aH, bH, acc1);
                acc2 = MFMA32(aH, bL, acc2);
                acc2 = MFMA32(aL, bH, acc2);
            }
        }
        __syncthreads();
    }

    // ---- Cs overlay: C layout col=lane&31, row=(reg&3)+8*(reg>>2)+4*oct ----
    float* Cs = (float*)lds;
#pragma unroll
    for (int i = 0; i < 16; i++) {
        int rowt = (i & 3) + 8 * (i >> 2) + 4 * oct;
        Cs[(tokg + rowt) * CS + expg + row31] = acc1[i] + acc2[i] * INV_LOSCALE;
    }
    __syncthreads();

    // ---- fused epilogue: one wave per token, lane = expert (verified R1-R4) ----
    const float blv = bl[lane];
    const float bnv = bn[lane];

    for (int t = wv; t < 64; t += 8) {
        const int gt = tok0 + t;
        float xr = Cs[t * CS + lane] + blv;
        float xf = Cs[t * CS + 64 + lane] + bnv;
        float nz = noise[(size_t)gt * NEXP + lane];

        // softplus (matches jax.nn.softplus)
        float stdv = fmaxf(xf, 0.f) + log1pf(expf(-fabsf(xf)));
        float noisy = fmaf(nz, stdv, xr);

        // full softmax over 64 lanes
        float m = noisy;
#pragma unroll
        for (int o = 32; o > 0; o >>= 1) m = fmaxf(m, __shfl_xor(m, o, 64));
        float p = expf(noisy - m);
        float s = p;
#pragma unroll
        for (int o = 32; o > 0; o >>= 1) s += __shfl_xor(s, o, 64);
        float fullp = p / s;

        // argmax #1 (ties -> lowest index, matching lax.top_k)
        float v = noisy; int idx = lane;
#pragma unroll
        for (int o = 32; o > 0; o >>= 1) {
            float ov = __shfl_xor(v, o, 64);
            int   oi = __shfl_xor(idx, o, 64);
            if (ov > v || (ov == v && oi < idx)) { v = ov; idx = oi; }
        }
        const float v1 = v; const int i1 = idx;
        // argmax #2
        v = (lane == i1) ? -INFINITY : noisy; idx = lane;
#pragma unroll
        for (int o = 32; o > 0; o >>= 1) {
            float ov = __shfl_xor(v, o, 64);
            int   oi = __shfl_xor(idx, o, 64);
            if (ov > v || (ov == v && oi < idx)) { v = ov; idx = oi; }
        }
        const float v2 = v; const int i2 = idx;

        // sparse softmax over {i1,i2}
        float e2 = expf(v2 - v1);
        float den = 1.f + e2;
        float routep = (lane == i1) ? (1.f / den) : ((lane == i2) ? (e2 / den) : 0.f);

        outR[(size_t)gt * NEXP + lane] = routep;
        outF[(size_t)gt * NEXP + lane] = fullp;
        if (lane == 0) {
            outIx[(size_t)gt * 2 + 0] = (float)i1;
            outIx[(size_t)gt * 2 + 1] = (float)i2;
        }
    }
}

extern "C" void kernel_launch(void* const* d_in, const int* in_sizes, int n_in,
                              void* d_out, int out_size, void* d_ws, size_t ws_size,
                              hipStream_t stream) {
    const float* h     = (const float*)d_in[0];
    const float* Wl    = (const float*)d_in[1];
    const float* bl    = (const float*)d_in[2];
    const float* Wn    = (const float*)d_in[3];
    const float* bn    = (const float*)d_in[4];
    const float* noise = (const float*)d_in[5];
    float* out = (float*)d_out;

    const int M = in_sizes[0] / DIM;                 // 32768
    float* outR  = out;                              // [M,64]
    float* outIx = out + (size_t)M * NEXP;           // [M,2]
    float* outF  = outIx + (size_t)M * 2;            // [M,64]

    router_fused<<<M / 64, 512, 0, stream>>>(h, Wl, bl, Wn, bn, noise,
                                             outR, outIx, outF, M);
}